// Round 5
// baseline (7050.456 us; speedup 1.0000x reference)
//
#include <hip/hip_runtime.h>

#define T_STEPS 8192
#define BATCH   128
#define HID     128
#define NTHR    64                // ONE wave per block: no barriers at all

typedef float v2f __attribute__((ext_vector_type(2)));

// tanh(z) = 1 - 2/(1+e^{2z}) -- 5 instrs, NaN-free at both infinities.
__device__ __forceinline__ float fast_tanh(float z) {
    float e = __expf(2.0f * z);
    float r = __builtin_amdgcn_rcpf(1.0f + e);
    return fmaf(-2.0f, r, 1.0f);
}

// full 64-lane wave sum of per-lane distinct values -> total in lane 63.
// 6 DPP add stages, all VALU pipe (no LDS, no barrier).
__device__ __forceinline__ float wave_sum_l63(float x) {
#define DPP_ADD(ctrl) do {                                                        \
        int t_ = __builtin_amdgcn_update_dpp(0, __builtin_bit_cast(int, x),       \
                                             (ctrl), 0xf, 0xf, false);            \
        x += __builtin_bit_cast(float, t_); } while (0)
    DPP_ADD(0x111);  // row_shr:1
    DPP_ADD(0x112);  // row_shr:2
    DPP_ADD(0x114);  // row_shr:4
    DPP_ADD(0x118);  // row_shr:8   -> 16-lane row sums at row tails
    DPP_ADD(0x142);  // row_bcast:15
    DPP_ADD(0x143);  // row_bcast:31 -> lane 63 holds wave total
#undef DPP_ADD
    return x;
}

__device__ __forceinline__ float bcast_lane(float v, int l) {
    int r = __builtin_amdgcn_readlane(__builtin_bit_cast(int, v), l);
    return __builtin_bit_cast(float, r);
}

#define FORALL64(M) M(0) M(1) M(2) M(3) M(4) M(5) M(6) M(7) \
    M(8) M(9) M(10) M(11) M(12) M(13) M(14) M(15) \
    M(16) M(17) M(18) M(19) M(20) M(21) M(22) M(23) \
    M(24) M(25) M(26) M(27) M(28) M(29) M(30) M(31) \
    M(32) M(33) M(34) M(35) M(36) M(37) M(38) M(39) \
    M(40) M(41) M(42) M(43) M(44) M(45) M(46) M(47) \
    M(48) M(49) M(50) M(51) M(52) M(53) M(54) M(55) \
    M(56) M(57) M(58) M(59) M(60) M(61) M(62) M(63)

// R19: single-wave scan. R18 post-mortem: ~900 of 1042 cyc/step was serial
// chain + the per-step 4-wave sync (lgkmcnt(0)+s_barrier+dyx broadcast-read
// latency + wave skew); DS-read traffic was only ~4.5 cyc/read marginal.
// One wave does all 16384 MACs/step: lane owns units (lane, lane+64) over
// FULL k=128 -> dots finish in-lane, h1 exchanged via broadcast LDS reads
// (same-address, conflict-free), dy = 6-DPP reduce + readlane. NO barrier,
// NO inter-wave exchange. Weights 256 floats/lane: 128 in VGPRs ("v" pins),
// 128 in AGPRs ("a" pins) -- gfx950 unified file, 1 wave/SIMD budget 512.
__global__ __launch_bounds__(NTHR, 1) void odenet_scan(
    const float* __restrict__ x,
    const float* __restrict__ W1, const float* __restrict__ b1,
    const float* __restrict__ W2, const float* __restrict__ b2,
    const float* __restrict__ W3, const float* __restrict__ b3,
    float* __restrict__ out) {

    const int b    = blockIdx.x;        // batch element
    const int lane = threadIdx.x;       // 0..63, single wave
    const int jA   = lane;              // owned output units
    const int jB   = lane + 64;

    __shared__ __align__(16) float h1buf[128];   // h1[k], k=0..127

    // ---- W2 columns jA, jB as v2f over k: wa_p={W2[2p][jA],W2[2p+1][jA]} ----
    const float* cA = W2 + jA;          // column jA, row stride HID
    const float* cB = W2 + jB;
#define DECLA(i) v2f wa##i = {cA[(2*(i)    ) * HID], cA[(2*(i) + 1) * HID]};
#define DECLB(i) v2f wb##i = {cB[(2*(i)    ) * HID], cB[(2*(i) + 1) * HID]};
    FORALL64(DECLA)
    FORALL64(DECLB)
#undef DECLA
#undef DECLB
#define PINA(i) asm volatile("" : "+v"(wa##i));
#define PINB(i) asm volatile("" : "+a"(wb##i));
    FORALL64(PINA)
    FORALL64(PINB)
#undef PINA
#undef PINB

    // layer-1 weights for the two h1 units this lane computes (k=lane, lane+64)
    float w1xa = W1[lane],      w1ya = W1[HID + lane],      b1a = b1[lane];
    float w1xb = W1[lane + 64], w1yb = W1[HID + lane + 64], b1b = b1[lane + 64];
    float b2A = b2[jA], b2B = b2[jB];
    float w3A = W3[jA], w3B = W3[jB], b3v = b3[0];
    asm volatile("" : "+v"(w1xa), "+v"(w1ya), "+v"(b1a),
                      "+v"(w1xb), "+v"(w1yb), "+v"(b1b),
                      "+v"(b2A), "+v"(b2B), "+v"(w3A), "+v"(w3B), "+v"(b3v));

    float y    = 0.0f;
    float ybuf = 0.0f;
    if (lane == 0) out[b] = 0.0f;       // y_0 = 0

    // ---- x double-buffer: xbuf = current 64-step block, xnext = next ----
    float xbuf  = x[lane * BATCH + b];                 // block 0
    int   nb    = 64;                                  // next block base
    float xnext = x[min(nb + lane, T_STEPS - 1) * BATCH + b];
    float xv = bcast_lane(xbuf, 0);
    float ax = fmaf(xv, w1xa, b1a);     // x-side of layer 1 for t=0
    float bx = fmaf(xv, w1xb, b1b);

    const float4* h4 = (const float4*)h1buf;

    for (int t = 0; t < T_STEPS - 1; ++t) {
        const int tm = t & 63;

        // ---- layer 1 (critical path from y: fma+tanh+write only) ----
        float ha = fast_tanh(fmaf(y, w1ya, ax));
        float hb = fast_tanh(fmaf(y, w1yb, bx));
        h1buf[lane]      = ha;          // k = lane      (2-way bank alias: free)
        h1buf[64 + lane] = hb;          // k = lane + 64

        // ---- layer 2: 32 BROADCAST b128 reads (all lanes same addr) ----
        // in-lane full-k dot for units jA, jB; 128 v_pk_fma_f32
        v2f a0 = {0.f, 0.f}, a1 = {0.f, 0.f};   // jA accumulators
        v2f c0 = {0.f, 0.f}, c1 = {0.f, 0.f};   // jB accumulators
        {
            float4 q;
#define FM(qi, A0, A1, B0, B1) q = h4[qi];                                        \
            { v2f lo = {q.x, q.y}, hi = {q.z, q.w};                               \
              a0 += A0 * lo; a1 += A1 * hi;                                       \
              c0 += B0 * lo; c1 += B1 * hi; }
            FM( 0, wa0 , wa1 , wb0 , wb1 ) FM( 1, wa2 , wa3 , wb2 , wb3 )
            FM( 2, wa4 , wa5 , wb4 , wb5 ) FM( 3, wa6 , wa7 , wb6 , wb7 )
            FM( 4, wa8 , wa9 , wb8 , wb9 ) FM( 5, wa10, wa11, wb10, wb11)
            FM( 6, wa12, wa13, wb12, wb13) FM( 7, wa14, wa15, wb14, wb15)
            FM( 8, wa16, wa17, wb16, wb17) FM( 9, wa18, wa19, wb18, wb19)
            FM(10, wa20, wa21, wb20, wb21) FM(11, wa22, wa23, wb22, wb23)
            FM(12, wa24, wa25, wb24, wb25) FM(13, wa26, wa27, wb26, wb27)
            FM(14, wa28, wa29, wb28, wb29) FM(15, wa30, wa31, wb30, wb31)
            FM(16, wa32, wa33, wb32, wb33) FM(17, wa34, wa35, wb34, wb35)
            FM(18, wa36, wa37, wb36, wb37) FM(19, wa38, wa39, wb38, wb39)
            FM(20, wa40, wa41, wb40, wb41) FM(21, wa42, wa43, wb42, wb43)
            FM(22, wa44, wa45, wb44, wb45) FM(23, wa46, wa47, wb46, wb47)
            FM(24, wa48, wa49, wb48, wb49) FM(25, wa50, wa51, wb50, wb51)
            FM(26, wa52, wa53, wb52, wb53) FM(27, wa54, wa55, wb54, wb55)
            FM(28, wa56, wa57, wb56, wb57) FM(29, wa58, wa59, wb58, wb59)
            FM(30, wa60, wa61, wb60, wb61) FM(31, wa62, wa63, wb62, wb63)
#undef FM
        }
        v2f as_ = a0 + a1;
        v2f cs_ = c0 + c1;

        // ---- next step's x-side prep (no deps; issues inside reduce chain) --
        const int tmn = (t + 1) & 63;
        if (tmn == 0) {                              // rotate x blocks
            xbuf = xnext;
            nb += 64;
            xnext = x[min(nb + lane, T_STEPS - 1) * BATCH + b];
        }
        float xvn = bcast_lane(xbuf, tmn);
        float axn = fmaf(xvn, w1xa, b1a);
        float bxn = fmaf(xvn, w1xb, b1b);

        // ---- full dots done in-lane: tanh, layer 3, wave reduce (VALU only) --
        float h2A = fast_tanh((as_.x + as_.y) + b2A);
        float h2B = fast_tanh((cs_.x + cs_.y) + b2B);
        float dyv = fmaf(w3A, h2A, w3B * h2B);       // per-lane: 2 units
        float dyw = wave_sum_l63(dyv);
        float dy  = bcast_lane(dyw, 63);             // all lanes get total

        y += dy + b3v;                               // DT = 1.0

        ybuf = (lane == tm) ? y : ybuf;
        if (tm == 63)
            out[(t - 62 + lane) * BATCH + b] = ybuf;

        ax = axn; bx = bxn;
    }
    // tail: t=8128..8190 captured y_8129..y_8191 in lanes 0..62
    if (lane < 63)
        out[(T_STEPS - 63 + lane) * BATCH + b] = ybuf;
}

extern "C" void kernel_launch(void* const* d_in, const int* in_sizes, int n_in,
                              void* d_out, int out_size, void* d_ws, size_t ws_size,
                              hipStream_t stream) {
    const float* x  = (const float*)d_in[0];
    const float* W1 = (const float*)d_in[1];
    const float* b1 = (const float*)d_in[2];
    const float* W2 = (const float*)d_in[3];
    const float* b2 = (const float*)d_in[4];
    const float* W3 = (const float*)d_in[5];
    const float* b3 = (const float*)d_in[6];

    odenet_scan<<<dim3(BATCH), dim3(NTHR), 0, stream>>>(
        x, W1, b1, W2, b2, W3, b3, (float*)d_out);
}

// Round 6
// 3650.481 us; speedup vs baseline: 1.9314x; 1.9314x over previous
//
#include <hip/hip_runtime.h>

#define T_STEPS 8192
#define BATCH   128
#define HID     128
#define NTHR    256               // 4 waves, 1/SIMD

typedef float v2f __attribute__((ext_vector_type(2)));

// tanh(z) = 1 - 2/(1+e^{2z}) -- 5 instrs, NaN-free at both infinities.
__device__ __forceinline__ float fast_tanh(float z) {
    float e = __expf(2.0f * z);
    float r = __builtin_amdgcn_rcpf(1.0f + e);
    return fmaf(-2.0f, r, 1.0f);
}

// butterfly sum across a quad (lanes 4q..4q+3): xor1 then xor2 quad_perm.
__device__ __forceinline__ float quad_sum(float x) {
    int t1 = __builtin_amdgcn_update_dpp(0, __builtin_bit_cast(int, x),
                                         0xB1 /*quad_perm [1,0,3,2]*/,
                                         0xf, 0xf, false);
    x += __builtin_bit_cast(float, t1);
    int t2 = __builtin_amdgcn_update_dpp(0, __builtin_bit_cast(int, x),
                                         0x4E /*quad_perm [2,3,0,1]*/,
                                         0xf, 0xf, false);
    return x + __builtin_bit_cast(float, t2);
}

// wave sum of QUAD-UNIFORM values -> total lands in lane 63 (4 DPP adds).
__device__ __forceinline__ float wave_sum_quaduniform_l63(float x) {
#define DPP_ADD(ctrl) do {                                                        \
        int t_ = __builtin_amdgcn_update_dpp(0, __builtin_bit_cast(int, x),       \
                                             (ctrl), 0xf, 0xf, false);            \
        x += __builtin_bit_cast(float, t_); } while (0)
    DPP_ADD(0x114);  // row_shr:4
    DPP_ADD(0x118);  // row_shr:8   -> row sums (one per quad) at row tails
    DPP_ADD(0x142);  // row_bcast:15
    DPP_ADD(0x143);  // row_bcast:31 -> lane 63 holds wave total
#undef DPP_ADD
    return x;
}

__device__ __forceinline__ float bcast_lane(float v, int l) {
    int r = __builtin_amdgcn_readlane(__builtin_bit_cast(int, v), l);
    return __builtin_bit_cast(float, r);
}

#define FORALL16(M) M(0) M(1) M(2) M(3) M(4) M(5) M(6) M(7) \
                    M(8) M(9) M(10) M(11) M(12) M(13) M(14) M(15)

// R20: force weight residency. R16-R18 report VGPR_Count 52-56 despite ~90
// live values -> the 64 pinned W2 floats/lane were SPILLED to scratch; the
// per-step scratch reloads (L1-thrashing, L2 latency) are the hidden wall
// (explains R17's exact-2x and R18's small gain). Fixes: launch_bounds(,1)
// -> 512-reg budget at our real occupancy (4 waves, 1/SIMD); in-loop
// read-pins make spill cost explicit to the allocator. Also: h1 stored
// k-interleaved (position 2*(k&63)+(k>>6), W2 rows permuted to match) so
// layer 1 does ONE ds_write_b64 instead of two b32; 16B pad per 32-float
// chunk keeps the 4 reader addr-groups on disjoint banks.
__global__ __launch_bounds__(NTHR, 1) void odenet_scan(
    const float* __restrict__ x,
    const float* __restrict__ W1, const float* __restrict__ b1,
    const float* __restrict__ W2, const float* __restrict__ b2,
    const float* __restrict__ W3, const float* __restrict__ b3,
    float* __restrict__ out) {

    const int b    = blockIdx.x;        // batch element
    const int tid  = threadIdx.x;
    const int w    = tid >> 6;          // wave 0..3
    const int lane = tid & 63;
    const int jg   = lane >> 2;         // j-pair group 0..15
    const int kc   = lane & 3;          // position-chunk [32*kc, 32*kc+32)
    const int j0   = (w << 5) | (jg << 1);     // owned output units j0, j0+1
    const int j1   = j0 + 1;
    const int kb2  = kc << 4;           // 16*kc: base k (low half) of chunk

    // wave-private h1: 4 chunks x 36 floats (32 + 4 pad -> chunk kc at byte
    // 144*kc; the 4 reader addr-groups land on disjoint 4-bank sets)
    __shared__ __align__(16) float h1buf[4][144];
    __shared__ __align__(16) float dyx[2][4];  // [parity][wave] dy partials

    // ---- W2 fragments for positions [32kc, 32kc+32) of columns j0, j1 ----
    // position p holds k = ((p&1)<<6)|(p>>1); float4 qi covers k =
    // {kb2+2qi, kb2+2qi+64, kb2+2qi+1, kb2+2qi+65}. Per j: 16 v2f with
    // wp_i = {W2[(kb2+i)*HID + j], W2[(kb2+i+64)*HID + j]}.
    const float* c0p = W2 + j0;         // column j0, row stride HID
    const float* c1p = W2 + j1;
#define DECLW(i) v2f wp##i = {c0p[(kb2 + (i)     ) * HID],                        \
                              c0p[(kb2 + (i) + 64) * HID]};                       \
                 v2f up##i = {c1p[(kb2 + (i)     ) * HID],                        \
                              c1p[(kb2 + (i) + 64) * HID]};
    FORALL16(DECLW)
#undef DECLW
#define PINW(i) asm volatile("" : "+v"(wp##i), "+v"(up##i));
    FORALL16(PINW)
#undef PINW

    // layer-1 weights for the two h1 units this lane computes (k=lane, lane+64)
    float w1xa = W1[lane],      w1ya = W1[HID + lane],      b1a = b1[lane];
    float w1xb = W1[lane + 64], w1yb = W1[HID + lane + 64], b1b = b1[lane + 64];
    float b2j0 = b2[j0], b2j1 = b2[j1];
    float w3j0 = W3[j0], w3j1 = W3[j1], b3v = b3[0];
    asm volatile("" : "+v"(w1xa), "+v"(w1ya), "+v"(b1a),
                      "+v"(w1xb), "+v"(w1yb), "+v"(b1b),
                      "+v"(b2j0), "+v"(b2j1), "+v"(w3j0), "+v"(w3j1), "+v"(b3v));

    float y    = 0.0f;
    float ybuf = 0.0f;                  // all waves capture (symmetric arrival)
    if (w == 0 && lane == 0) out[b] = 0.0f;   // y_0 = 0

    // ---- x double-buffer: xbuf = current 64-step block, xnext = next ----
    float xbuf  = x[lane * BATCH + b];                 // block 0
    int   nb    = 64;                                  // next block base
    float xnext = x[min(nb + lane, T_STEPS - 1) * BATCH + b];
    float xv = bcast_lane(xbuf, 0);
    float ax = fmaf(xv, w1xa, b1a);     // x-side of layer 1 for t=0
    float bx = fmaf(xv, w1xb, b1b);

    // writer: positions (2*lane, 2*lane+1) -> float offset 2*lane + 4*(lane>>4)
    float2* h1w = (float2*)(&h1buf[w][0] + 2 * lane + 4 * (lane >> 4));
    // reader: chunk kc at byte 144*kc
    const float4* h4 = (const float4*)((const char*)&h1buf[w][0] + 144 * kc);

    for (int t = 0; t < T_STEPS - 1; ++t) {
        const int tm = t & 63;

        // ---- layer 1 (critical path from y: fma+tanh+ONE b64 write) ----
        float ha = fast_tanh(fmaf(y, w1ya, ax));
        float hb = fast_tanh(fmaf(y, w1yb, bx));
        *h1w = make_float2(ha, hb);     // positions 2*lane (k=lane), +1 (k=lane+64)

        // weights must be VGPR-resident here (zero-instr read pins)
        asm volatile("" :: "v"(wp0), "v"(wp1), "v"(wp2), "v"(wp3),
                           "v"(wp4), "v"(wp5), "v"(wp6), "v"(wp7),
                           "v"(wp8), "v"(wp9), "v"(wp10), "v"(wp11),
                           "v"(wp12), "v"(wp13), "v"(wp14), "v"(wp15));
        asm volatile("" :: "v"(up0), "v"(up1), "v"(up2), "v"(up3),
                           "v"(up4), "v"(up5), "v"(up6), "v"(up7),
                           "v"(up8), "v"(up9), "v"(up10), "v"(up11),
                           "v"(up12), "v"(up13), "v"(up14), "v"(up15));

        // ---- layer 2: 8 b128 reads of own 32-pos chunk, reused for j0 & j1 --
        v2f a0 = {0.f, 0.f}, a1 = {0.f, 0.f};   // j0 accumulators
        v2f c0 = {0.f, 0.f}, c1 = {0.f, 0.f};   // j1 accumulators
        {
            float4 q;
#define FMAP(qi, WA, WB, UA, UB) q = h4[qi];                                      \
            { v2f lo = {q.x, q.y}, hi = {q.z, q.w};                               \
              a0 += WA * lo; a1 += WB * hi;                                       \
              c0 += UA * lo; c1 += UB * hi; }
            FMAP(0, wp0 , wp1 , up0 , up1 ) FMAP(1, wp2 , wp3 , up2 , up3 )
            FMAP(2, wp4 , wp5 , up4 , up5 ) FMAP(3, wp6 , wp7 , up6 , up7 )
            FMAP(4, wp8 , wp9 , up8 , up9 ) FMAP(5, wp10, wp11, up10, up11)
            FMAP(6, wp12, wp13, up12, up13) FMAP(7, wp14, wp15, up14, up15)
#undef FMAP
        }
        v2f as_ = a0 + a1;
        v2f cs_ = c0 + c1;

        // ---- k-reduce across the quad (2 DPP levels), tanh, layer 3 ----
        float z0 = quad_sum(as_.x + as_.y);          // full dot for unit j0
        float z1 = quad_sum(cs_.x + cs_.y);          // full dot for unit j1
        float h20 = fast_tanh(z0 + b2j0);
        float h21 = fast_tanh(z1 + b2j1);
        float dyv = fmaf(w3j0, h20, w3j1 * h21);     // quad-uniform
        float dyw = wave_sum_quaduniform_l63(dyv);
        if (lane == 63) dyx[t & 1][w] = dyw;         // direct from lane 63

        // ---- next step's x-side prep (y-independent; fills barrier wait) ----
        const int tmn = (t + 1) & 63;
        if (tmn == 0) {                              // rotate x blocks
            xbuf = xnext;
            nb += 64;
            xnext = x[min(nb + lane, T_STEPS - 1) * BATCH + b];
        }
        float xvn = bcast_lane(xbuf, tmn);
        float axn = fmaf(xvn, w1xa, b1a);
        float bxn = fmaf(xvn, w1xb, b1b);

        // ---- lgkm-only barrier (4 waves): stores/x-loads stay in flight ----
        asm volatile("s_waitcnt lgkmcnt(0)\n\ts_barrier" ::: "memory");

        float4 d = *(const float4*)&dyx[t & 1][0];   // one broadcast b128
        y += ((d.x + d.y) + (d.z + d.w)) + b3v;      // DT = 1.0

        ybuf = (lane == tm) ? y : ybuf;              // all waves (symmetric)
        if (w == 0 && tm == 63)
            out[(t - 62 + lane) * BATCH + b] = ybuf;

        ax = axn; bx = bxn;
    }
    // tail: t=8128..8190 captured y_8129..y_8191 in lanes 0..62
    if (w == 0 && lane < 63)
        out[(T_STEPS - 63 + lane) * BATCH + b] = ybuf;
}

extern "C" void kernel_launch(void* const* d_in, const int* in_sizes, int n_in,
                              void* d_out, int out_size, void* d_ws, size_t ws_size,
                              hipStream_t stream) {
    const float* x  = (const float*)d_in[0];
    const float* W1 = (const float*)d_in[1];
    const float* b1 = (const float*)d_in[2];
    const float* W2 = (const float*)d_in[3];
    const float* b2 = (const float*)d_in[4];
    const float* W3 = (const float*)d_in[5];
    const float* b3 = (const float*)d_in[6];

    odenet_scan<<<dim3(BATCH), dim3(NTHR), 0, stream>>>(
        x, W1, b1, W2, b2, W3, b3, (float*)d_out);
}

// Round 7
// 3599.718 us; speedup vs baseline: 1.9586x; 1.0141x over previous
//
#include <hip/hip_runtime.h>

#define T_STEPS 8192
#define BATCH   128
#define HID     128
#define NTHR    256               // 4 waves, 1/SIMD

typedef float v2f __attribute__((ext_vector_type(2)));

// tanh(z) = 1 - 2/(1+e^{2z}) -- 5 instrs, NaN-free at both infinities.
__device__ __forceinline__ float fast_tanh(float z) {
    float e = __expf(2.0f * z);
    float r = __builtin_amdgcn_rcpf(1.0f + e);
    return fmaf(-2.0f, r, 1.0f);
}

// butterfly sum across a quad (lanes 4q..4q+3): xor1 then xor2 quad_perm.
__device__ __forceinline__ float quad_sum(float x) {
    int t1 = __builtin_amdgcn_update_dpp(0, __builtin_bit_cast(int, x),
                                         0xB1 /*quad_perm [1,0,3,2]*/,
                                         0xf, 0xf, false);
    x += __builtin_bit_cast(float, t1);
    int t2 = __builtin_amdgcn_update_dpp(0, __builtin_bit_cast(int, x),
                                         0x4E /*quad_perm [2,3,0,1]*/,
                                         0xf, 0xf, false);
    return x + __builtin_bit_cast(float, t2);
}

// wave sum of QUAD-UNIFORM values -> total lands in lane 63 (4 DPP adds).
__device__ __forceinline__ float wave_sum_quaduniform_l63(float x) {
#define DPP_ADD(ctrl) do {                                                        \
        int t_ = __builtin_amdgcn_update_dpp(0, __builtin_bit_cast(int, x),       \
                                             (ctrl), 0xf, 0xf, false);            \
        x += __builtin_bit_cast(float, t_); } while (0)
    DPP_ADD(0x114);  // row_shr:4
    DPP_ADD(0x118);  // row_shr:8   -> row sums (one per quad) at row tails
    DPP_ADD(0x142);  // row_bcast:15
    DPP_ADD(0x143);  // row_bcast:31 -> lane 63 holds wave total
#undef DPP_ADD
    return x;
}

__device__ __forceinline__ float bcast_lane(float v, int l) {
    int r = __builtin_amdgcn_readlane(__builtin_bit_cast(int, v), l);
    return __builtin_bit_cast(float, r);
}

#define FORALL16(M) M(0) M(1) M(2) M(3) M(4) M(5) M(6) M(7) \
                    M(8) M(9) M(10) M(11) M(12) M(13) M(14) M(15)

// R21: AGPR-pin the W2 fragments. R20 post-mortem: VGPR_Count=56 is
// incompatible with 64 resident weight floats/lane -> the "+v" pins were
// satisfied by per-iteration reloads (scratch/L2), ~500 cyc/step of hidden
// VMEM latency (the unexplained gap in the cycle model). R19 proved "+a"
// pins allocate for real (VGPR_Count=256). gfx950 unified RF: AGPRs are the
// same pool; VALU sources acc regs (or compiler inserts cheap accvgpr_read).
// Everything else identical to R20.
__global__ __launch_bounds__(NTHR, 1) void odenet_scan(
    const float* __restrict__ x,
    const float* __restrict__ W1, const float* __restrict__ b1,
    const float* __restrict__ W2, const float* __restrict__ b2,
    const float* __restrict__ W3, const float* __restrict__ b3,
    float* __restrict__ out) {

    const int b    = blockIdx.x;        // batch element
    const int tid  = threadIdx.x;
    const int w    = tid >> 6;          // wave 0..3
    const int lane = tid & 63;
    const int jg   = lane >> 2;         // j-pair group 0..15
    const int kc   = lane & 3;          // position-chunk [32*kc, 32*kc+32)
    const int j0   = (w << 5) | (jg << 1);     // owned output units j0, j0+1
    const int j1   = j0 + 1;
    const int kb2  = kc << 4;           // 16*kc: base k (low half) of chunk

    // wave-private h1: 4 chunks x 36 floats (32 + 4 pad -> chunk kc at byte
    // 144*kc; the 4 reader addr-groups land on disjoint 4-bank sets)
    __shared__ __align__(16) float h1buf[4][144];
    __shared__ __align__(16) float dyx[2][4];  // [parity][wave] dy partials

    // ---- W2 fragments for positions [32kc, 32kc+32) of columns j0, j1 ----
    // position p holds k = ((p&1)<<6)|(p>>1); float4 qi covers k =
    // {kb2+2qi, kb2+2qi+64, kb2+2qi+1, kb2+2qi+65}. Per j: 16 v2f with
    // wp_i = {W2[(kb2+i)*HID + j], W2[(kb2+i+64)*HID + j]}.
    const float* c0p = W2 + j0;         // column j0, row stride HID
    const float* c1p = W2 + j1;
#define DECLW(i) v2f wp##i = {c0p[(kb2 + (i)     ) * HID],                        \
                              c0p[(kb2 + (i) + 64) * HID]};                       \
                 v2f up##i = {c1p[(kb2 + (i)     ) * HID],                        \
                              c1p[(kb2 + (i) + 64) * HID]};
    FORALL16(DECLW)
#undef DECLW
#define PINW(i) asm volatile("" : "+a"(wp##i), "+a"(up##i));
    FORALL16(PINW)
#undef PINW

    // layer-1 weights for the two h1 units this lane computes (k=lane, lane+64)
    float w1xa = W1[lane],      w1ya = W1[HID + lane],      b1a = b1[lane];
    float w1xb = W1[lane + 64], w1yb = W1[HID + lane + 64], b1b = b1[lane + 64];
    float b2j0 = b2[j0], b2j1 = b2[j1];
    float w3j0 = W3[j0], w3j1 = W3[j1], b3v = b3[0];
    asm volatile("" : "+v"(w1xa), "+v"(w1ya), "+v"(b1a),
                      "+v"(w1xb), "+v"(w1yb), "+v"(b1b),
                      "+v"(b2j0), "+v"(b2j1), "+v"(w3j0), "+v"(w3j1), "+v"(b3v));

    float y    = 0.0f;
    float ybuf = 0.0f;                  // all waves capture (symmetric arrival)
    if (w == 0 && lane == 0) out[b] = 0.0f;   // y_0 = 0

    // ---- x double-buffer: xbuf = current 64-step block, xnext = next ----
    float xbuf  = x[lane * BATCH + b];                 // block 0
    int   nb    = 64;                                  // next block base
    float xnext = x[min(nb + lane, T_STEPS - 1) * BATCH + b];
    float xv = bcast_lane(xbuf, 0);
    float ax = fmaf(xv, w1xa, b1a);     // x-side of layer 1 for t=0
    float bx = fmaf(xv, w1xb, b1b);

    // writer: positions (2*lane, 2*lane+1) -> float offset 2*lane + 4*(lane>>4)
    float2* h1w = (float2*)(&h1buf[w][0] + 2 * lane + 4 * (lane >> 4));
    // reader: chunk kc at byte 144*kc
    const float4* h4 = (const float4*)((const char*)&h1buf[w][0] + 144 * kc);

    for (int t = 0; t < T_STEPS - 1; ++t) {
        const int tm = t & 63;

        // ---- layer 1 (critical path from y: fma+tanh+ONE b64 write) ----
        float ha = fast_tanh(fmaf(y, w1ya, ax));
        float hb = fast_tanh(fmaf(y, w1yb, bx));
        *h1w = make_float2(ha, hb);     // positions 2*lane (k=lane), +1 (k=lane+64)

        // zero-instruction anchor: weights must sit in AGPRs here
        asm volatile("" :: "a"(wp0), "a"(wp1), "a"(wp2), "a"(wp3),
                           "a"(wp4), "a"(wp5), "a"(wp6), "a"(wp7),
                           "a"(wp8), "a"(wp9), "a"(wp10), "a"(wp11),
                           "a"(wp12), "a"(wp13), "a"(wp14), "a"(wp15));
        asm volatile("" :: "a"(up0), "a"(up1), "a"(up2), "a"(up3),
                           "a"(up4), "a"(up5), "a"(up6), "a"(up7),
                           "a"(up8), "a"(up9), "a"(up10), "a"(up11),
                           "a"(up12), "a"(up13), "a"(up14), "a"(up15));

        // ---- layer 2: 8 b128 reads of own 32-pos chunk, reused for j0 & j1 --
        v2f a0 = {0.f, 0.f}, a1 = {0.f, 0.f};   // j0 accumulators
        v2f c0 = {0.f, 0.f}, c1 = {0.f, 0.f};   // j1 accumulators
        {
            float4 q;
#define FMAP(qi, WA, WB, UA, UB) q = h4[qi];                                      \
            { v2f lo = {q.x, q.y}, hi = {q.z, q.w};                               \
              a0 += WA * lo; a1 += WB * hi;                                       \
              c0 += UA * lo; c1 += UB * hi; }
            FMAP(0, wp0 , wp1 , up0 , up1 ) FMAP(1, wp2 , wp3 , up2 , up3 )
            FMAP(2, wp4 , wp5 , up4 , up5 ) FMAP(3, wp6 , wp7 , up6 , up7 )
            FMAP(4, wp8 , wp9 , up8 , up9 ) FMAP(5, wp10, wp11, up10, up11)
            FMAP(6, wp12, wp13, up12, up13) FMAP(7, wp14, wp15, up14, up15)
#undef FMAP
        }
        v2f as_ = a0 + a1;
        v2f cs_ = c0 + c1;

        // ---- k-reduce across the quad (2 DPP levels), tanh, layer 3 ----
        float z0 = quad_sum(as_.x + as_.y);          // full dot for unit j0
        float z1 = quad_sum(cs_.x + cs_.y);          // full dot for unit j1
        float h20 = fast_tanh(z0 + b2j0);
        float h21 = fast_tanh(z1 + b2j1);
        float dyv = fmaf(w3j0, h20, w3j1 * h21);     // quad-uniform
        float dyw = wave_sum_quaduniform_l63(dyv);
        if (lane == 63) dyx[t & 1][w] = dyw;         // direct from lane 63

        // ---- next step's x-side prep (y-independent; fills barrier wait) ----
        const int tmn = (t + 1) & 63;
        if (tmn == 0) {                              // rotate x blocks
            xbuf = xnext;
            nb += 64;
            xnext = x[min(nb + lane, T_STEPS - 1) * BATCH + b];
        }
        float xvn = bcast_lane(xbuf, tmn);
        float axn = fmaf(xvn, w1xa, b1a);
        float bxn = fmaf(xvn, w1xb, b1b);

        // ---- lgkm-only barrier (4 waves): stores/x-loads stay in flight ----
        asm volatile("s_waitcnt lgkmcnt(0)\n\ts_barrier" ::: "memory");

        float4 d = *(const float4*)&dyx[t & 1][0];   // one broadcast b128
        y += ((d.x + d.y) + (d.z + d.w)) + b3v;      // DT = 1.0

        ybuf = (lane == tm) ? y : ybuf;              // all waves (symmetric)
        if (w == 0 && tm == 63)
            out[(t - 62 + lane) * BATCH + b] = ybuf;

        ax = axn; bx = bxn;
    }
    // tail: t=8128..8190 captured y_8129..y_8191 in lanes 0..62
    if (w == 0 && lane < 63)
        out[(T_STEPS - 63 + lane) * BATCH + b] = ybuf;
}

extern "C" void kernel_launch(void* const* d_in, const int* in_sizes, int n_in,
                              void* d_out, int out_size, void* d_ws, size_t ws_size,
                              hipStream_t stream) {
    const float* x  = (const float*)d_in[0];
    const float* W1 = (const float*)d_in[1];
    const float* b1 = (const float*)d_in[2];
    const float* W2 = (const float*)d_in[3];
    const float* b2 = (const float*)d_in[4];
    const float* W3 = (const float*)d_in[5];
    const float* b3 = (const float*)d_in[6];

    odenet_scan<<<dim3(BATCH), dim3(NTHR), 0, stream>>>(
        x, W1, b1, W2, b2, W3, b3, (float*)d_out);
}